// Round 1
// baseline (1190.110 us; speedup 1.0000x reference)
//
#include <hip/hip_runtime.h>

#define TOK     50176   // 1024 windows * 49 tokens
#define NQKV    1152
#define DMODEL  384
#define HW      3136    // 56*56
#define NWIN    1024

// ---------------------------------------------------------------------------
// Kernel 1: qkv = window_gather(x) @ Wqkv + bqkv
//   x:    (16, 384, 56, 56) fp32 channel-major
//   Wqkv: (384, 1152) row-major
//   qkv:  (50176, 1152) row-major (token-major)
// 64x64 output tile, BK=16, 256 threads, 4x4 micro-tile per thread.
// ---------------------------------------------------------------------------
__global__ void qkv_gemm(const float* __restrict__ x, const float* __restrict__ W,
                         const float* __restrict__ bias, float* __restrict__ qkv) {
  __shared__ __align__(16) float As[16][64];
  __shared__ __align__(16) float Bs[16][64];
  const int tid = threadIdx.x;
  const int bn = blockIdx.x << 6;   // output col base (0..1151)
  const int bm = blockIdx.y << 6;   // output row base (token)

  const int m  = tid & 63;          // token / col lane within tile
  const int kr = tid >> 6;          // 0..3, k-row group

  // window gather address for token (bm + m)
  const unsigned gm  = bm + m;
  const unsigned win = gm / 49u;
  const unsigned tt  = gm - win * 49u;
  const unsigned bb  = win >> 6;
  const unsigned wh  = (win >> 3) & 7u;
  const unsigned ww  = win & 7u;
  const unsigned r   = tt / 7u;
  const unsigned c   = tt - r * 7u;
  const float* xbase = x + (size_t)bb * (DMODEL * HW) + (wh * 7 + r) * 56 + (ww * 7 + c);
  const float* wbase = W + bn + m;

  float acc[4][4] = {{0.f, 0.f, 0.f, 0.f}, {0.f, 0.f, 0.f, 0.f},
                     {0.f, 0.f, 0.f, 0.f}, {0.f, 0.f, 0.f, 0.f}};
  const int ty = tid >> 4, tx = tid & 15;

  for (int k0 = 0; k0 < DMODEL; k0 += 16) {
#pragma unroll
    for (int i = 0; i < 4; ++i) {
      const int kk = kr + (i << 2);
      As[kk][m] = xbase[(size_t)(k0 + kk) * HW];
      Bs[kk][m] = wbase[(size_t)(k0 + kk) * NQKV];
    }
    __syncthreads();
#pragma unroll
    for (int kk = 0; kk < 16; ++kk) {
      const float4 av = *(const float4*)&As[kk][ty << 2];
      const float4 bv = *(const float4*)&Bs[kk][tx << 2];
      acc[0][0] += av.x * bv.x; acc[0][1] += av.x * bv.y; acc[0][2] += av.x * bv.z; acc[0][3] += av.x * bv.w;
      acc[1][0] += av.y * bv.x; acc[1][1] += av.y * bv.y; acc[1][2] += av.y * bv.z; acc[1][3] += av.y * bv.w;
      acc[2][0] += av.z * bv.x; acc[2][1] += av.z * bv.y; acc[2][2] += av.z * bv.z; acc[2][3] += av.z * bv.w;
      acc[3][0] += av.w * bv.x; acc[3][1] += av.w * bv.y; acc[3][2] += av.w * bv.z; acc[3][3] += av.w * bv.w;
    }
    __syncthreads();
  }

  const float4 bv = *(const float4*)&bias[bn + (tx << 2)];
#pragma unroll
  for (int i = 0; i < 4; ++i) {
    float4 o;
    o.x = acc[i][0] + bv.x; o.y = acc[i][1] + bv.y;
    o.z = acc[i][2] + bv.z; o.w = acc[i][3] + bv.w;
    *(float4*)&qkv[(size_t)(bm + (ty << 2) + i) * NQKV + bn + (tx << 2)] = o;
  }
}

// ---------------------------------------------------------------------------
// Kernel 2: per-(window, head) attention.
//   qkv:   (50176, 1152); q at col h*32, k at 384+h*32, v at 768+h*32
//   attnT: (384, 50176) K-major output so proj GEMM A-loads coalesce
// 128 threads per block, grid (1024, 12).
// ---------------------------------------------------------------------------
__global__ void attn_kernel(const float* __restrict__ qkv, float* __restrict__ attnT) {
  const int win  = blockIdx.x;
  const int head = blockIdx.y;
  const int tid  = threadIdx.x;

  __shared__ float qs[49][33];
  __shared__ float ks[49][33];
  __shared__ float vs[49][33];
  __shared__ float ss[49][50];

  const float* base = qkv + (size_t)win * 49 * NQKV + head * 32;
  for (int idx = tid; idx < 49 * 32; idx += 128) {
    const int t = idx >> 5, d = idx & 31;
    const float* row = base + (size_t)t * NQKV + d;
    qs[t][d] = row[0];
    ks[t][d] = row[384];
    vs[t][d] = row[768];
  }
  __syncthreads();

  const float scale = 0.17677669529663687f;  // 1/sqrt(32)
  for (int idx = tid; idx < 49 * 49; idx += 128) {
    const int i = idx / 49;
    const int j = idx - i * 49;
    float acc = 0.f;
#pragma unroll
    for (int d = 0; d < 32; ++d) acc += qs[i][d] * ks[j][d];
    ss[i][j] = acc * scale;
  }
  __syncthreads();

  if (tid < 49) {
    float mx = -1e30f;
    for (int j = 0; j < 49; ++j) mx = fmaxf(mx, ss[tid][j]);
    float sum = 0.f;
    for (int j = 0; j < 49; ++j) {
      const float e = __expf(ss[tid][j] - mx);
      ss[tid][j] = e;
      sum += e;
    }
    const float inv = 1.f / sum;
    for (int j = 0; j < 49; ++j) ss[tid][j] *= inv;
  }
  __syncthreads();

  for (int idx = tid; idx < 32 * 49; idx += 128) {
    const int d = idx / 49;
    const int t = idx - d * 49;
    float acc = 0.f;
#pragma unroll
    for (int j = 0; j < 49; ++j) acc += ss[t][j] * vs[j][d];
    attnT[(size_t)(head * 32 + d) * TOK + win * 49 + t] = acc;
  }
}

// ---------------------------------------------------------------------------
// Kernel 3: out = attn_out @ Wproj + bproj, scattered back to (16,384,56,56).
//   A (attnT): (384, 50176) K-major -> coalesced A-tile loads
//   Wproj: (384, 384) row-major
// ---------------------------------------------------------------------------
__global__ void proj_gemm(const float* __restrict__ A, const float* __restrict__ W,
                          const float* __restrict__ bias, float* __restrict__ out) {
  __shared__ __align__(16) float As[16][64];
  __shared__ __align__(16) float Bs[16][64];
  const int tid = threadIdx.x;
  const int bn = blockIdx.x << 6;   // output channel base (0..383)
  const int bm = blockIdx.y << 6;   // token base

  const int m  = tid & 63;
  const int kr = tid >> 6;

  const float* abase = A + bm + m;   // + k*TOK
  const float* wbase = W + bn + m;   // + k*DMODEL

  float acc[4][4] = {{0.f, 0.f, 0.f, 0.f}, {0.f, 0.f, 0.f, 0.f},
                     {0.f, 0.f, 0.f, 0.f}, {0.f, 0.f, 0.f, 0.f}};
  const int ty = tid >> 4, tx = tid & 15;

  for (int k0 = 0; k0 < DMODEL; k0 += 16) {
#pragma unroll
    for (int i = 0; i < 4; ++i) {
      const int kk = kr + (i << 2);
      As[kk][m] = abase[(size_t)(k0 + kk) * TOK];
      Bs[kk][m] = wbase[(size_t)(k0 + kk) * DMODEL];
    }
    __syncthreads();
#pragma unroll
    for (int kk = 0; kk < 16; ++kk) {
      const float4 av = *(const float4*)&As[kk][ty << 2];
      const float4 bv = *(const float4*)&Bs[kk][tx << 2];
      acc[0][0] += av.x * bv.x; acc[0][1] += av.x * bv.y; acc[0][2] += av.x * bv.z; acc[0][3] += av.x * bv.w;
      acc[1][0] += av.y * bv.x; acc[1][1] += av.y * bv.y; acc[1][2] += av.y * bv.z; acc[1][3] += av.y * bv.w;
      acc[2][0] += av.z * bv.x; acc[2][1] += av.z * bv.y; acc[2][2] += av.z * bv.z; acc[2][3] += av.z * bv.w;
      acc[3][0] += av.w * bv.x; acc[3][1] += av.w * bv.y; acc[3][2] += av.w * bv.z; acc[3][3] += av.w * bv.w;
    }
    __syncthreads();
  }

  const float4 bv = *(const float4*)&bias[bn + (tx << 2)];
#pragma unroll
  for (int i = 0; i < 4; ++i) {
    const unsigned gm  = bm + (ty << 2) + i;
    const unsigned win = gm / 49u;
    const unsigned tt  = gm - win * 49u;
    const unsigned bb  = win >> 6;
    const unsigned wh  = (win >> 3) & 7u;
    const unsigned ww  = win & 7u;
    const unsigned r   = tt / 7u;
    const unsigned c   = tt - r * 7u;
    float* obase = out + (size_t)bb * (DMODEL * HW) + (wh * 7 + r) * 56 + (ww * 7 + c);
    const unsigned j0 = bn + (tx << 2);
    obase[(size_t)(j0 + 0) * HW] = acc[i][0] + bv.x;
    obase[(size_t)(j0 + 1) * HW] = acc[i][1] + bv.y;
    obase[(size_t)(j0 + 2) * HW] = acc[i][2] + bv.z;
    obase[(size_t)(j0 + 3) * HW] = acc[i][3] + bv.w;
  }
}

extern "C" void kernel_launch(void* const* d_in, const int* in_sizes, int n_in,
                              void* d_out, int out_size, void* d_ws, size_t ws_size,
                              hipStream_t stream) {
  const float* x     = (const float*)d_in[0];
  const float* Wqkv  = (const float*)d_in[1];
  const float* bqkv  = (const float*)d_in[2];
  const float* Wproj = (const float*)d_in[3];
  const float* bproj = (const float*)d_in[4];
  float* out = (float*)d_out;

  float* qkv   = (float*)d_ws;                          // 50176*1152 fp32 = 231 MB
  float* attnT = qkv + (size_t)TOK * NQKV;              // 384*50176  fp32 =  77 MB

  qkv_gemm<<<dim3(NQKV / 64, TOK / 64), 256, 0, stream>>>(x, Wqkv, bqkv, qkv);
  attn_kernel<<<dim3(NWIN, 12), 128, 0, stream>>>(qkv, attnT);
  proj_gemm<<<dim3(DMODEL / 64, TOK / 64), 256, 0, stream>>>(attnT, Wproj, bproj, out);
}

// Round 2
// 712.188 us; speedup vs baseline: 1.6711x; 1.6711x over previous
//
#include <hip/hip_runtime.h>

#define TOK     50176
#define NQKV    1152
#define DMODEL  384
#define HW      3136
#define NWIN    1024

typedef __bf16 bf16x8 __attribute__((ext_vector_type(8)));
typedef float  f32x4  __attribute__((ext_vector_type(4)));

__device__ __forceinline__ __bf16 f2bf(float f) {            // round-to-nearest-even
  unsigned u = __float_as_uint(f);
  u += 0x7fffu + ((u >> 16) & 1u);
  unsigned short s = (unsigned short)(u >> 16);
  return __builtin_bit_cast(__bf16, s);
}
__device__ __forceinline__ float bf2f(__bf16 b) {
  return __uint_as_float(((unsigned)__builtin_bit_cast(unsigned short, b)) << 16);
}
__device__ __forceinline__ void gload_lds16(const void* g, void* l) {
  __builtin_amdgcn_global_load_lds(
      (const __attribute__((address_space(1))) unsigned int*)g,
      (__attribute__((address_space(3))) unsigned int*)l, 16, 0, 0);
}

// ---------------------------------------------------------------------------
// Gather x (16,384,56,56) fp32 -> Xw (50176, 384) bf16 token-major.
// ---------------------------------------------------------------------------
__global__ void gather_x(const float* __restrict__ x, __bf16* __restrict__ Xw) {
  const int idx = blockIdx.x * 256 + threadIdx.x;     // one thread per 4 w-elems
  const int e = idx << 2;
  const int w = e % 56;
  int tmp = e / 56;
  const int h = tmp % 56; tmp /= 56;
  const int ch = tmp % 384;
  const int b  = tmp / 384;
  const float4 v = *(const float4*)(x + (size_t)e);
  const float vv[4] = {v.x, v.y, v.z, v.w};
#pragma unroll
  for (int k = 0; k < 4; ++k) {
    const int ww  = w + k;
    const int win = b * 64 + (h / 7) * 8 + ww / 7;
    const int tt  = (h % 7) * 7 + ww % 7;
    Xw[(size_t)(win * 49 + tt) * DMODEL + ch] = f2bf(vv[k]);
  }
}

// Transpose+convert weights: WqkvT (1152,384) bf16, WprojT (384,384) bf16.
__global__ void conv_w(const float* __restrict__ Wqkv, const float* __restrict__ Wproj,
                       __bf16* __restrict__ WqkvT, __bf16* __restrict__ WprojT) {
  const int idx = blockIdx.x * 256 + threadIdx.x;
  if (idx < DMODEL * NQKV) {
    const int k = idx / NQKV, n = idx % NQKV;
    WqkvT[(size_t)n * DMODEL + k] = f2bf(Wqkv[idx]);
  }
  if (idx < DMODEL * DMODEL) {
    const int k = idx / DMODEL, n = idx % DMODEL;
    WprojT[(size_t)n * DMODEL + k] = f2bf(Wproj[idx]);
  }
}

// ---------------------------------------------------------------------------
// bf16 MFMA GEMM, 128x128 tile, BK=32, 256 threads (4 waves, 2x2 of 64x64),
// double-buffered LDS staged via global_load_lds width-16. K = 384 fixed.
// A: (M,384) bf16 row-major. BT: (N,384) bf16 row-major (B transposed).
// EPI 0: C -> bf16 row-major (M x Ncols) + bias.
// EPI 1: C -> fp32 scatter to (16,384,56,56) + bias (proj epilogue).
// ---------------------------------------------------------------------------
template <int EPI>
__global__ __launch_bounds__(256) void gemm128(const __bf16* __restrict__ A,
                                               const __bf16* __restrict__ BT,
                                               const float* __restrict__ bias,
                                               void* __restrict__ Cout, int Ncols) {
  __shared__ __align__(16) __bf16 As[2][128 * 32];
  __shared__ __align__(16) __bf16 Bs[2][128 * 32];
  const int tid  = threadIdx.x;
  const int lane = tid & 63;
  const int wid  = tid >> 6;
  const int bm = blockIdx.y << 7;
  const int bn = blockIdx.x << 7;

  // staging source pointers (row = c*64 + tid>>2, kp = tid&3)
  const __bf16* a0 = A  + (size_t)(bm +      (tid >> 2)) * DMODEL + ((tid & 3) << 3);
  const __bf16* a1 = A  + (size_t)(bm + 64 + (tid >> 2)) * DMODEL + ((tid & 3) << 3);
  const __bf16* b0 = BT + (size_t)(bn +      (tid >> 2)) * DMODEL + ((tid & 3) << 3);
  const __bf16* b1 = BT + (size_t)(bn + 64 + (tid >> 2)) * DMODEL + ((tid & 3) << 3);

  const int wm = (wid >> 1) << 6;
  const int wn = (wid & 1) << 6;
  const int lrow = lane & 15;
  const int lk8  = (lane >> 4) << 3;

  f32x4 acc[4][4] = {};

  auto stage = [&](int buf, int kt) {
    const int koff = kt << 5;
    gload_lds16(a0 + koff, &As[buf][(wid << 9)]);
    gload_lds16(a1 + koff, &As[buf][2048 + (wid << 9)]);
    gload_lds16(b0 + koff, &Bs[buf][(wid << 9)]);
    gload_lds16(b1 + koff, &Bs[buf][2048 + (wid << 9)]);
  };

  stage(0, 0);
#pragma unroll 1
  for (int kt = 0; kt < 12; ++kt) {
    __syncthreads();                       // drains vmcnt -> buf[kt&1] ready
    if (kt + 1 < 12) stage((kt + 1) & 1, kt + 1);
    const __bf16* pA = &As[kt & 1][(wm + lrow) * 32 + lk8];
    const __bf16* pB = &Bs[kt & 1][(wn + lrow) * 32 + lk8];
    bf16x8 av[4], bv[4];
#pragma unroll
    for (int i = 0; i < 4; ++i) av[i] = *(const bf16x8*)(pA + i * 16 * 32);
#pragma unroll
    for (int j = 0; j < 4; ++j) bv[j] = *(const bf16x8*)(pB + j * 16 * 32);
#pragma unroll
    for (int i = 0; i < 4; ++i)
#pragma unroll
      for (int j = 0; j < 4; ++j)
        acc[i][j] = __builtin_amdgcn_mfma_f32_16x16x32_bf16(av[i], bv[j], acc[i][j], 0, 0, 0);
  }

  const int col0 = bn + wn + (lane & 15);
  const int row0 = bm + wm + ((lane >> 4) << 2);

  if (EPI == 0) {
    __bf16* out = (__bf16*)Cout;
#pragma unroll
    for (int i = 0; i < 4; ++i)
#pragma unroll
      for (int r = 0; r < 4; ++r) {
        const int token = row0 + i * 16 + r;
#pragma unroll
        for (int j = 0; j < 4; ++j) {
          const int col = col0 + j * 16;
          out[(size_t)token * Ncols + col] = f2bf(acc[i][j][r] + bias[col]);
        }
      }
  } else {
    float* out = (float*)Cout;
#pragma unroll
    for (int i = 0; i < 4; ++i)
#pragma unroll
      for (int r = 0; r < 4; ++r) {
        const unsigned token = row0 + i * 16 + r;
        const unsigned win = token / 49u;
        const unsigned tt  = token - win * 49u;
        const unsigned bb  = win >> 6;
        const unsigned wh  = (win >> 3) & 7u;
        const unsigned ww  = win & 7u;
        const unsigned rr  = tt / 7u;
        const unsigned cc  = tt - rr * 7u;
        const unsigned sp  = (wh * 7 + rr) * 56 + ww * 7 + cc;
        float* obase = out + (size_t)bb * (DMODEL * HW) + sp;
#pragma unroll
        for (int j = 0; j < 4; ++j) {
          const int ch = col0 + j * 16;
          obase[(size_t)ch * HW] = acc[i][j][r] + bias[ch];
        }
      }
  }
}

// ---------------------------------------------------------------------------
// Attention per (window, head): fp32 VALU, bf16 in/out.
// ---------------------------------------------------------------------------
__global__ void attn_kernel(const __bf16* __restrict__ qkv, __bf16* __restrict__ attnO) {
  const int win  = blockIdx.x;
  const int head = blockIdx.y;
  const int tid  = threadIdx.x;

  __shared__ float qs[49][33];
  __shared__ float ks[49][33];
  __shared__ float vs[49][33];
  __shared__ float ss[49][50];

  const __bf16* base = qkv + (size_t)win * 49 * NQKV + head * 32;
  for (int idx = tid; idx < 49 * 32; idx += 128) {
    const int t = idx >> 5, d = idx & 31;
    const __bf16* row = base + (size_t)t * NQKV + d;
    qs[t][d] = bf2f(row[0]);
    ks[t][d] = bf2f(row[384]);
    vs[t][d] = bf2f(row[768]);
  }
  __syncthreads();

  const float scale = 0.17677669529663687f;
  for (int idx = tid; idx < 49 * 49; idx += 128) {
    const int i = idx / 49;
    const int j = idx - i * 49;
    float acc = 0.f;
#pragma unroll
    for (int d = 0; d < 32; ++d) acc += qs[i][d] * ks[j][d];
    ss[i][j] = acc * scale;
  }
  __syncthreads();

  if (tid < 49) {
    float mx = -1e30f;
    for (int j = 0; j < 49; ++j) mx = fmaxf(mx, ss[tid][j]);
    float sum = 0.f;
    for (int j = 0; j < 49; ++j) {
      const float e = __expf(ss[tid][j] - mx);
      ss[tid][j] = e;
      sum += e;
    }
    const float inv = 1.f / sum;
    for (int j = 0; j < 49; ++j) ss[tid][j] *= inv;
  }
  __syncthreads();

  for (int idx = tid; idx < 49 * 32; idx += 128) {
    const int t = idx >> 5, d = idx & 31;
    float acc = 0.f;
#pragma unroll
    for (int j = 0; j < 49; ++j) acc += ss[t][j] * vs[j][d];
    attnO[(size_t)(win * 49 + t) * DMODEL + head * 32 + d] = f2bf(acc);
  }
}

extern "C" void kernel_launch(void* const* d_in, const int* in_sizes, int n_in,
                              void* d_out, int out_size, void* d_ws, size_t ws_size,
                              hipStream_t stream) {
  const float* x     = (const float*)d_in[0];
  const float* Wqkv  = (const float*)d_in[1];
  const float* bqkv  = (const float*)d_in[2];
  const float* Wproj = (const float*)d_in[3];
  const float* bproj = (const float*)d_in[4];
  float* out = (float*)d_out;

  char* ws = (char*)d_ws;
  __bf16* Xw     = (__bf16*)ws;                      ws += (size_t)TOK * DMODEL * 2;   // 38.5 MB
  __bf16* qkvb   = (__bf16*)ws;                      ws += (size_t)TOK * NQKV * 2;     // 115.6 MB
  __bf16* attnO  = (__bf16*)ws;                      ws += (size_t)TOK * DMODEL * 2;   // 38.5 MB
  __bf16* WqkvT  = (__bf16*)ws;                      ws += (size_t)NQKV * DMODEL * 2;  // 0.88 MB
  __bf16* WprojT = (__bf16*)ws;

  gather_x<<<18816, 256, 0, stream>>>(x, Xw);
  conv_w<<<1728, 256, 0, stream>>>(Wqkv, Wproj, WqkvT, WprojT);
  gemm128<0><<<dim3(NQKV / 128, TOK / 128), 256, 0, stream>>>(Xw, WqkvT, bqkv, qkvb, NQKV);
  attn_kernel<<<dim3(NWIN, 12), 128, 0, stream>>>(qkvb, attnO);
  gemm128<1><<<dim3(DMODEL / 128, TOK / 128), 256, 0, stream>>>(attnO, WprojT, bproj, out, DMODEL);
}

// Round 3
// 334.447 us; speedup vs baseline: 3.5584x; 2.1294x over previous
//
#include <hip/hip_runtime.h>

#define TOK     50176
#define NQKV    1152
#define DMODEL  384
#define HW      3136
#define NWIN    1024

typedef __bf16 bf16x8 __attribute__((ext_vector_type(8)));
typedef float  f32x4  __attribute__((ext_vector_type(4)));

__device__ __forceinline__ __bf16 f2bf(float f) {            // round-to-nearest-even
  unsigned u = __float_as_uint(f);
  u += 0x7fffu + ((u >> 16) & 1u);
  unsigned short s = (unsigned short)(u >> 16);
  return __builtin_bit_cast(__bf16, s);
}
__device__ __forceinline__ unsigned short f2bfu(float f) {
  return __builtin_bit_cast(unsigned short, f2bf(f));
}
__device__ __forceinline__ void gload_lds16(const void* g, void* l) {
  __builtin_amdgcn_global_load_lds(
      (const __attribute__((address_space(1))) unsigned int*)g,
      (__attribute__((address_space(3))) unsigned int*)l, 16, 0, 0);
}

// ---------------------------------------------------------------------------
// Gather x (16,384,56,56) fp32 -> Xw (50176, 384) bf16 token-major.
// Block: (chtile of 48, window-row of 8 windows, batch). Coalesced float4
// reads -> LDS [392 tok][48 ch] -> coalesced 16B stores.
// ---------------------------------------------------------------------------
__global__ __launch_bounds__(256) void gather_x(const float* __restrict__ x,
                                                __bf16* __restrict__ Xw) {
  __shared__ __bf16 lt[392 * 48];
  const int ct = blockIdx.x, hr = blockIdx.y, b = blockIdx.z;
  const int tid = threadIdx.x;
  const float* xb = x + ((size_t)(b * 384 + ct * 48)) * HW + hr * 7 * 56;

  for (int u = tid; u < 48 * 7 * 14; u += 256) {          // 4704 float4 units
    const int ch = u / 98, rem = u % 98;
    const int h7 = rem / 14, w4 = rem % 14;
    const float4 v = *(const float4*)&xb[(size_t)ch * HW + h7 * 56 + 4 * w4];
    const float vv[4] = {v.x, v.y, v.z, v.w};
#pragma unroll
    for (int e = 0; e < 4; ++e) {
      const int w = 4 * w4 + e;
      const int t = (w / 7) * 49 + h7 * 7 + (w % 7);
      lt[t * 48 + ch] = f2bf(vv[e]);
    }
  }
  __syncthreads();

  const size_t tokbase = (size_t)(b * 64 + hr * 8) * 49;
  for (int u = tid; u < 392 * 6; u += 256) {              // 2352 16B units
    const int t = u / 6, c6 = u % 6;
    const bf16x8 vv = *(const bf16x8*)&lt[t * 48 + 8 * c6];
    *(bf16x8*)&Xw[(tokbase + t) * DMODEL + ct * 48 + 8 * c6] = vv;
  }
}

// Transpose+convert weights: WqkvT (1152,384) bf16, WprojT (384,384) bf16.
__global__ void conv_w(const float* __restrict__ Wqkv, const float* __restrict__ Wproj,
                       __bf16* __restrict__ WqkvT, __bf16* __restrict__ WprojT) {
  const int idx = blockIdx.x * 256 + threadIdx.x;
  if (idx < DMODEL * NQKV) {
    const int k = idx / NQKV, n = idx % NQKV;
    WqkvT[(size_t)n * DMODEL + k] = f2bf(Wqkv[idx]);
  }
  if (idx < DMODEL * DMODEL) {
    const int k = idx / DMODEL, n = idx % DMODEL;
    WprojT[(size_t)n * DMODEL + k] = f2bf(Wproj[idx]);
  }
}

// ---------------------------------------------------------------------------
// bf16 MFMA GEMM, 128x128 tile, BK=32, 256 threads (4 waves, 2x2 of 64x64),
// double-buffered LDS staged via global_load_lds width-16. K = 384 fixed.
// EPI 0: C -> bf16 row-major + bias. EPI 1: C -> fp32 scatter to NCHW + bias.
// ---------------------------------------------------------------------------
template <int EPI>
__global__ __launch_bounds__(256) void gemm128(const __bf16* __restrict__ A,
                                               const __bf16* __restrict__ BT,
                                               const float* __restrict__ bias,
                                               void* __restrict__ Cout, int Ncols) {
  __shared__ __align__(16) __bf16 As[2][128 * 32];
  __shared__ __align__(16) __bf16 Bs[2][128 * 32];
  const int tid  = threadIdx.x;
  const int lane = tid & 63;
  const int wid  = tid >> 6;
  const int bm = blockIdx.y << 7;
  const int bn = blockIdx.x << 7;

  const __bf16* a0 = A  + (size_t)(bm +      (tid >> 2)) * DMODEL + ((tid & 3) << 3);
  const __bf16* a1 = A  + (size_t)(bm + 64 + (tid >> 2)) * DMODEL + ((tid & 3) << 3);
  const __bf16* b0 = BT + (size_t)(bn +      (tid >> 2)) * DMODEL + ((tid & 3) << 3);
  const __bf16* b1 = BT + (size_t)(bn + 64 + (tid >> 2)) * DMODEL + ((tid & 3) << 3);

  const int wm = (wid >> 1) << 6;
  const int wn = (wid & 1) << 6;
  const int lrow = lane & 15;
  const int lk8  = (lane >> 4) << 3;

  f32x4 acc[4][4] = {};

  auto stage = [&](int buf, int kt) {
    const int koff = kt << 5;
    gload_lds16(a0 + koff, &As[buf][(wid << 9)]);
    gload_lds16(a1 + koff, &As[buf][2048 + (wid << 9)]);
    gload_lds16(b0 + koff, &Bs[buf][(wid << 9)]);
    gload_lds16(b1 + koff, &Bs[buf][2048 + (wid << 9)]);
  };

  stage(0, 0);
#pragma unroll 1
  for (int kt = 0; kt < 12; ++kt) {
    __syncthreads();
    if (kt + 1 < 12) stage((kt + 1) & 1, kt + 1);
    const __bf16* pA = &As[kt & 1][(wm + lrow) * 32 + lk8];
    const __bf16* pB = &Bs[kt & 1][(wn + lrow) * 32 + lk8];
    bf16x8 av[4], bv[4];
#pragma unroll
    for (int i = 0; i < 4; ++i) av[i] = *(const bf16x8*)(pA + i * 16 * 32);
#pragma unroll
    for (int j = 0; j < 4; ++j) bv[j] = *(const bf16x8*)(pB + j * 16 * 32);
#pragma unroll
    for (int i = 0; i < 4; ++i)
#pragma unroll
      for (int j = 0; j < 4; ++j)
        acc[i][j] = __builtin_amdgcn_mfma_f32_16x16x32_bf16(av[i], bv[j], acc[i][j], 0, 0, 0);
  }

  const int col0 = bn + wn + (lane & 15);
  const int row0 = bm + wm + ((lane >> 4) << 2);

  if (EPI == 0) {
    __bf16* out = (__bf16*)Cout;
#pragma unroll
    for (int i = 0; i < 4; ++i)
#pragma unroll
      for (int r = 0; r < 4; ++r) {
        const int token = row0 + i * 16 + r;
#pragma unroll
        for (int j = 0; j < 4; ++j) {
          const int col = col0 + j * 16;
          out[(size_t)token * Ncols + col] = f2bf(acc[i][j][r] + bias[col]);
        }
      }
  } else {
    float* out = (float*)Cout;
#pragma unroll
    for (int i = 0; i < 4; ++i)
#pragma unroll
      for (int r = 0; r < 4; ++r) {
        const unsigned token = row0 + i * 16 + r;
        const unsigned win = token / 49u;
        const unsigned tt  = token - win * 49u;
        const unsigned bb  = win >> 6;
        const unsigned wh  = (win >> 3) & 7u;
        const unsigned ww  = win & 7u;
        const unsigned rr  = tt / 7u;
        const unsigned cc  = tt - rr * 7u;
        const unsigned sp  = (wh * 7 + rr) * 56 + ww * 7 + cc;
        float* obase = out + (size_t)bb * (DMODEL * HW) + sp;
#pragma unroll
        for (int j = 0; j < 4; ++j) {
          const int ch = col0 + j * 16;
          obase[(size_t)ch * HW] = acc[i][j][r] + bias[ch];
        }
      }
  }
}

// ---------------------------------------------------------------------------
// MFMA attention: one wave per (window, head). Pad 49 -> 64.
// S^T = mfma(K, Q); wave-parallel softmax (in-lane + 2 shfl_xor);
// P -> LDS [q][k] (pitch 72, bank-balanced); V^T -> LDS [d][k];
// O^T = mfma(V^T, P^T) with both operands as contiguous ds_read_b128.
// ---------------------------------------------------------------------------
__global__ __launch_bounds__(64) void attn_mfma(const __bf16* __restrict__ qkv,
                                                __bf16* __restrict__ attnO) {
  __shared__ __align__(16) __bf16 lds[96 * 72];   // p: [64][72]; vt: [32][72]
  __bf16* p_lds = lds;
  __bf16* vt    = lds + 64 * 72;

  const int lane = threadIdx.x;
  const int win  = blockIdx.x;
  const int h    = blockIdx.y;
  const int lr = lane & 15, g = lane >> 4;
  const size_t rowbase = (size_t)win * 49;

  int rr[4];
#pragma unroll
  for (int f = 0; f < 4; ++f) rr[f] = (16 * f + lr > 48) ? 48 : (16 * f + lr);

  const int co = h * 32 + 8 * g;

  // K (A-operand) and Q (B-operand) fragments, 16B loads
  bf16x8 av[4], bv[4];
#pragma unroll
  for (int f = 0; f < 4; ++f) {
    const __bf16* rp = qkv + (rowbase + rr[f]) * NQKV + co;
    av[f] = *(const bf16x8*)(rp + 384);
    bv[f] = *(const bf16x8*)(rp);
  }

  // V staging loads: 392 8B units (k 0..48, d-quad 0..7)
  ushort4 vreg[7];
#pragma unroll
  for (int u = 0; u < 7; ++u) {
    const int unit = lane + (u << 6);
    if (unit < 392) {
      const int k = unit >> 3, dq = unit & 7;
      vreg[u] = *(const ushort4*)(qkv + (rowbase + k) * NQKV + 768 + h * 32 + 4 * dq);
    }
  }

  // S^T = K @ Q^T : acc[i][j], key = 16i+4g+r, q = 16j+lr
  f32x4 acc[4][4] = {};
#pragma unroll
  for (int i = 0; i < 4; ++i)
#pragma unroll
    for (int j = 0; j < 4; ++j)
      acc[i][j] = __builtin_amdgcn_mfma_f32_16x16x32_bf16(av[i], bv[j], acc[i][j], 0, 0, 0);

  // scale + key-mask
  const float scale = 0.17677669529663687f;
#pragma unroll
  for (int i = 0; i < 4; ++i)
#pragma unroll
    for (int j = 0; j < 4; ++j)
#pragma unroll
      for (int r = 0; r < 4; ++r) {
        float v = acc[i][j][r] * scale;
        if (i == 3 && (4 * g + r) != 0) v = -1e30f;   // keys 49..63
        acc[i][j][r] = v;
      }

  // write V^T to LDS: vt[d][k]
#pragma unroll
  for (int u = 0; u < 7; ++u) {
    const int unit = lane + (u << 6);
    if (unit < 392) {
      const int k = unit >> 3, dq = unit & 7;
      const ushort4 vv = vreg[u];
      vt[(4 * dq + 0) * 72 + k] = __builtin_bit_cast(__bf16, vv.x);
      vt[(4 * dq + 1) * 72 + k] = __builtin_bit_cast(__bf16, vv.y);
      vt[(4 * dq + 2) * 72 + k] = __builtin_bit_cast(__bf16, vv.z);
      vt[(4 * dq + 3) * 72 + k] = __builtin_bit_cast(__bf16, vv.w);
    }
  }

  // softmax over keys for each q-column (j, lr): in-lane 16 + shfl over g
#pragma unroll
  for (int j = 0; j < 4; ++j) {
    float mx = -1e30f;
#pragma unroll
    for (int i = 0; i < 4; ++i)
#pragma unroll
      for (int r = 0; r < 4; ++r) mx = fmaxf(mx, acc[i][j][r]);
    mx = fmaxf(mx, __shfl_xor(mx, 16));
    mx = fmaxf(mx, __shfl_xor(mx, 32));
    float sum = 0.f;
#pragma unroll
    for (int i = 0; i < 4; ++i)
#pragma unroll
      for (int r = 0; r < 4; ++r) {
        const float e = __expf(acc[i][j][r] - mx);
        acc[i][j][r] = e;
        sum += e;
      }
    sum += __shfl_xor(sum, 16);
    sum += __shfl_xor(sum, 32);
    const float inv = 1.f / sum;
#pragma unroll
    for (int i = 0; i < 4; ++i) {
      ushort4 pk;
      pk.x = f2bfu(acc[i][j][0] * inv);
      pk.y = f2bfu(acc[i][j][1] * inv);
      pk.z = f2bfu(acc[i][j][2] * inv);
      pk.w = f2bfu(acc[i][j][3] * inv);
      *(ushort4*)&p_lds[(16 * j + lr) * 72 + 16 * i + 4 * g] = pk;   // P[q][16i+4g+r]
    }
  }

  // O^T = V^T @ P^T : o[i2][j2], d = 16*i2+4g+r, q = 16*j2+lr
  f32x4 o[2][4] = {};
#pragma unroll
  for (int ks = 0; ks < 2; ++ks) {
    bf16x8 a2[2], b2[4];
#pragma unroll
    for (int i2 = 0; i2 < 2; ++i2)
      a2[i2] = *(const bf16x8*)&vt[(16 * i2 + lr) * 72 + 32 * ks + 8 * g];
#pragma unroll
    for (int j2 = 0; j2 < 4; ++j2)
      b2[j2] = *(const bf16x8*)&p_lds[(16 * j2 + lr) * 72 + 32 * ks + 8 * g];
#pragma unroll
    for (int i2 = 0; i2 < 2; ++i2)
#pragma unroll
      for (int j2 = 0; j2 < 4; ++j2)
        o[i2][j2] = __builtin_amdgcn_mfma_f32_16x16x32_bf16(a2[i2], b2[j2], o[i2][j2], 0, 0, 0);
  }

  // store O^T -> attnO[token][ch], 8B packed over 4 consecutive channels
#pragma unroll
  for (int j2 = 0; j2 < 4; ++j2) {
    const int q = 16 * j2 + lr;
    if (q <= 48) {
#pragma unroll
      for (int i2 = 0; i2 < 2; ++i2) {
        ushort4 ok;
        ok.x = f2bfu(o[i2][j2][0]);
        ok.y = f2bfu(o[i2][j2][1]);
        ok.z = f2bfu(o[i2][j2][2]);
        ok.w = f2bfu(o[i2][j2][3]);
        *(ushort4*)&attnO[(rowbase + q) * DMODEL + h * 32 + 16 * i2 + 4 * g] = ok;
      }
    }
  }
}

extern "C" void kernel_launch(void* const* d_in, const int* in_sizes, int n_in,
                              void* d_out, int out_size, void* d_ws, size_t ws_size,
                              hipStream_t stream) {
  const float* x     = (const float*)d_in[0];
  const float* Wqkv  = (const float*)d_in[1];
  const float* bqkv  = (const float*)d_in[2];
  const float* Wproj = (const float*)d_in[3];
  const float* bproj = (const float*)d_in[4];
  float* out = (float*)d_out;

  char* ws = (char*)d_ws;
  __bf16* Xw     = (__bf16*)ws;  ws += (size_t)TOK * DMODEL * 2;
  __bf16* qkvb   = (__bf16*)ws;  ws += (size_t)TOK * NQKV * 2;
  __bf16* attnO  = (__bf16*)ws;  ws += (size_t)TOK * DMODEL * 2;
  __bf16* WqkvT  = (__bf16*)ws;  ws += (size_t)NQKV * DMODEL * 2;
  __bf16* WprojT = (__bf16*)ws;

  gather_x<<<dim3(8, 8, 16), 256, 0, stream>>>(x, Xw);
  conv_w<<<1728, 256, 0, stream>>>(Wqkv, Wproj, WqkvT, WprojT);
  gemm128<0><<<dim3(NQKV / 128, TOK / 128), 256, 0, stream>>>(Xw, WqkvT, bqkv, qkvb, NQKV);
  attn_mfma<<<dim3(NWIN, 12), 64, 0, stream>>>(qkvb, attnO);
  gemm128<1><<<dim3(DMODEL / 128, TOK / 128), 256, 0, stream>>>(attnO, WprojT, bproj, out, DMODEL);
}

// Round 4
// 243.947 us; speedup vs baseline: 4.8786x; 1.3710x over previous
//
#include <hip/hip_runtime.h>

#define TOK     50176
#define NQKV    1152
#define DMODEL  384
#define HW      3136
#define NWIN    1024

typedef __bf16 bf16x8 __attribute__((ext_vector_type(8)));
typedef float  f32x4  __attribute__((ext_vector_type(4)));

__device__ __forceinline__ __bf16 f2bf(float f) {            // round-to-nearest-even
  unsigned u = __float_as_uint(f);
  u += 0x7fffu + ((u >> 16) & 1u);
  unsigned short s = (unsigned short)(u >> 16);
  return __builtin_bit_cast(__bf16, s);
}
__device__ __forceinline__ unsigned short f2bfu(float f) {
  return __builtin_bit_cast(unsigned short, f2bf(f));
}
__device__ __forceinline__ float bf2f(__bf16 b) {
  return __uint_as_float(((unsigned)__builtin_bit_cast(unsigned short, b)) << 16);
}
__device__ __forceinline__ void gload_lds16(const void* g, void* l) {
  __builtin_amdgcn_global_load_lds(
      (const __attribute__((address_space(1))) unsigned int*)g,
      (__attribute__((address_space(3))) unsigned int*)l, 16, 0, 0);
}

// ---------------------------------------------------------------------------
// Gather x (16,384,56,56) fp32 -> Xw (50176, 384) bf16 token-major.
// ---------------------------------------------------------------------------
__global__ __launch_bounds__(256) void gather_x(const float* __restrict__ x,
                                                __bf16* __restrict__ Xw) {
  __shared__ __bf16 lt[392 * 48];
  const int ct = blockIdx.x, hr = blockIdx.y, b = blockIdx.z;
  const int tid = threadIdx.x;
  const float* xb = x + ((size_t)(b * 384 + ct * 48)) * HW + hr * 7 * 56;

  for (int u = tid; u < 48 * 7 * 14; u += 256) {
    const int ch = u / 98, rem = u % 98;
    const int h7 = rem / 14, w4 = rem % 14;
    const float4 v = *(const float4*)&xb[(size_t)ch * HW + h7 * 56 + 4 * w4];
    const float vv[4] = {v.x, v.y, v.z, v.w};
#pragma unroll
    for (int e = 0; e < 4; ++e) {
      const int w = 4 * w4 + e;
      const int t = (w / 7) * 49 + h7 * 7 + (w % 7);
      lt[t * 48 + ch] = f2bf(vv[e]);
    }
  }
  __syncthreads();

  const size_t tokbase = (size_t)(b * 64 + hr * 8) * 49;
  for (int u = tid; u < 392 * 6; u += 256) {
    const int t = u / 6, c6 = u % 6;
    const bf16x8 vv = *(const bf16x8*)&lt[t * 48 + 8 * c6];
    *(bf16x8*)&Xw[(tokbase + t) * DMODEL + ct * 48 + 8 * c6] = vv;
  }
}

// ---------------------------------------------------------------------------
// Unscatter: attnP (50176,384) bf16 token-major -> out (16,384,56,56) fp32.
// Exact inverse of gather_x. Bias already folded into attnP by proj GEMM.
// ---------------------------------------------------------------------------
__global__ __launch_bounds__(256) void unscatter(const __bf16* __restrict__ P,
                                                 float* __restrict__ out) {
  __shared__ __bf16 lt[392 * 48];
  const int ct = blockIdx.x, hr = blockIdx.y, b = blockIdx.z;
  const int tid = threadIdx.x;
  const size_t tokbase = (size_t)(b * 64 + hr * 8) * 49;

  for (int u = tid; u < 392 * 6; u += 256) {
    const int t = u / 6, c6 = u % 6;
    *(bf16x8*)&lt[t * 48 + 8 * c6] =
        *(const bf16x8*)&P[(tokbase + t) * DMODEL + ct * 48 + 8 * c6];
  }
  __syncthreads();

  float* ob = out + ((size_t)(b * 384 + ct * 48)) * HW + hr * 7 * 56;
  for (int u = tid; u < 48 * 98; u += 256) {
    const int ch = u / 98, rem = u % 98;
    const int h7 = rem / 14, w4 = rem % 14;
    float4 o;
    float* oo = (float*)&o;
#pragma unroll
    for (int e = 0; e < 4; ++e) {
      const int w = 4 * w4 + e;
      const int t = (w / 7) * 49 + h7 * 7 + (w % 7);
      oo[e] = bf2f(lt[t * 48 + ch]);
    }
    *(float4*)&ob[(size_t)ch * HW + h7 * 56 + 4 * w4] = o;
  }
}

// Transpose+convert weights: WqkvT (1152,384) bf16, WprojT (384,384) bf16.
__global__ void conv_w(const float* __restrict__ Wqkv, const float* __restrict__ Wproj,
                       __bf16* __restrict__ WqkvT, __bf16* __restrict__ WprojT) {
  const int idx = blockIdx.x * 256 + threadIdx.x;
  if (idx < DMODEL * NQKV) {
    const int k = idx / NQKV, n = idx % NQKV;
    WqkvT[(size_t)n * DMODEL + k] = f2bf(Wqkv[idx]);
  }
  if (idx < DMODEL * DMODEL) {
    const int k = idx / DMODEL, n = idx % DMODEL;
    WprojT[(size_t)n * DMODEL + k] = f2bf(Wproj[idx]);
  }
}

// ---------------------------------------------------------------------------
// bf16 MFMA GEMM, 128x128 tile, BK=32, 256 threads (4 waves, 2x2 of 64x64),
// double-buffered LDS via global_load_lds width-16. K = 384 fixed.
// Transposed accumulator: acc[j][i] = mfma(bv[j], av[i]) -> row=channel,
// col=token; each thread packs 4 consecutive channels -> ushort4 stores
// (32B contiguous per g-group). C written bf16 token-major + bias.
// ---------------------------------------------------------------------------
__global__ __launch_bounds__(256) void gemm128(const __bf16* __restrict__ A,
                                               const __bf16* __restrict__ BT,
                                               const float* __restrict__ bias,
                                               __bf16* __restrict__ Cout, int Ncols) {
  __shared__ __align__(16) __bf16 As[2][128 * 32];
  __shared__ __align__(16) __bf16 Bs[2][128 * 32];
  const int tid  = threadIdx.x;
  const int lane = tid & 63;
  const int wid  = tid >> 6;
  const int bm = blockIdx.y << 7;
  const int bn = blockIdx.x << 7;

  const __bf16* a0 = A  + (size_t)(bm +      (tid >> 2)) * DMODEL + ((tid & 3) << 3);
  const __bf16* a1 = A  + (size_t)(bm + 64 + (tid >> 2)) * DMODEL + ((tid & 3) << 3);
  const __bf16* b0 = BT + (size_t)(bn +      (tid >> 2)) * DMODEL + ((tid & 3) << 3);
  const __bf16* b1 = BT + (size_t)(bn + 64 + (tid >> 2)) * DMODEL + ((tid & 3) << 3);

  const int wm = (wid >> 1) << 6;
  const int wn = (wid & 1) << 6;
  const int lrow = lane & 15;
  const int lk8  = (lane >> 4) << 3;

  f32x4 acc[4][4] = {};   // acc[j][i]: j = channel frag, i = token frag

  auto stage = [&](int buf, int kt) {
    const int koff = kt << 5;
    gload_lds16(a0 + koff, &As[buf][(wid << 9)]);
    gload_lds16(a1 + koff, &As[buf][2048 + (wid << 9)]);
    gload_lds16(b0 + koff, &Bs[buf][(wid << 9)]);
    gload_lds16(b1 + koff, &Bs[buf][2048 + (wid << 9)]);
  };

  stage(0, 0);
#pragma unroll 1
  for (int kt = 0; kt < 12; ++kt) {
    __syncthreads();
    if (kt + 1 < 12) stage((kt + 1) & 1, kt + 1);
    const __bf16* pA = &As[kt & 1][(wm + lrow) * 32 + lk8];
    const __bf16* pB = &Bs[kt & 1][(wn + lrow) * 32 + lk8];
    bf16x8 av[4], bv[4];
#pragma unroll
    for (int i = 0; i < 4; ++i) av[i] = *(const bf16x8*)(pA + i * 16 * 32);
#pragma unroll
    for (int j = 0; j < 4; ++j) bv[j] = *(const bf16x8*)(pB + j * 16 * 32);
#pragma unroll
    for (int i = 0; i < 4; ++i)
#pragma unroll
      for (int j = 0; j < 4; ++j)
        acc[j][i] = __builtin_amdgcn_mfma_f32_16x16x32_bf16(bv[j], av[i], acc[j][i], 0, 0, 0);
  }

  const int lr = lane & 15, g = lane >> 4;
  const int tok0 = bm + wm + lr;
  const int ch0  = bn + wn + (g << 2);

#pragma unroll
  for (int j = 0; j < 4; ++j) {
    const int ch = ch0 + 16 * j;
    const float4 b4 = *(const float4*)&bias[ch];
#pragma unroll
    for (int i = 0; i < 4; ++i) {
      const int token = tok0 + 16 * i;
      ushort4 pk;
      pk.x = f2bfu(acc[j][i][0] + b4.x);
      pk.y = f2bfu(acc[j][i][1] + b4.y);
      pk.z = f2bfu(acc[j][i][2] + b4.z);
      pk.w = f2bfu(acc[j][i][3] + b4.w);
      *(ushort4*)&Cout[(size_t)token * Ncols + ch] = pk;
    }
  }
}

// ---------------------------------------------------------------------------
// MFMA attention: one wave per (window, head). Pad 49 -> 64. (unchanged)
// ---------------------------------------------------------------------------
__global__ __launch_bounds__(64) void attn_mfma(const __bf16* __restrict__ qkv,
                                                __bf16* __restrict__ attnO) {
  __shared__ __align__(16) __bf16 lds[96 * 72];
  __bf16* p_lds = lds;
  __bf16* vt    = lds + 64 * 72;

  const int lane = threadIdx.x;
  const int win  = blockIdx.x;
  const int h    = blockIdx.y;
  const int lr = lane & 15, g = lane >> 4;
  const size_t rowbase = (size_t)win * 49;

  int rr[4];
#pragma unroll
  for (int f = 0; f < 4; ++f) rr[f] = (16 * f + lr > 48) ? 48 : (16 * f + lr);

  const int co = h * 32 + 8 * g;

  bf16x8 av[4], bv[4];
#pragma unroll
  for (int f = 0; f < 4; ++f) {
    const __bf16* rp = qkv + (rowbase + rr[f]) * NQKV + co;
    av[f] = *(const bf16x8*)(rp + 384);
    bv[f] = *(const bf16x8*)(rp);
  }

  ushort4 vreg[7];
#pragma unroll
  for (int u = 0; u < 7; ++u) {
    const int unit = lane + (u << 6);
    if (unit < 392) {
      const int k = unit >> 3, dq = unit & 7;
      vreg[u] = *(const ushort4*)(qkv + (rowbase + k) * NQKV + 768 + h * 32 + 4 * dq);
    }
  }

  f32x4 acc[4][4] = {};
#pragma unroll
  for (int i = 0; i < 4; ++i)
#pragma unroll
    for (int j = 0; j < 4; ++j)
      acc[i][j] = __builtin_amdgcn_mfma_f32_16x16x32_bf16(av[i], bv[j], acc[i][j], 0, 0, 0);

  const float scale = 0.17677669529663687f;
#pragma unroll
  for (int i = 0; i < 4; ++i)
#pragma unroll
    for (int j = 0; j < 4; ++j)
#pragma unroll
      for (int r = 0; r < 4; ++r) {
        float v = acc[i][j][r] * scale;
        if (i == 3 && (4 * g + r) != 0) v = -1e30f;
        acc[i][j][r] = v;
      }

#pragma unroll
  for (int u = 0; u < 7; ++u) {
    const int unit = lane + (u << 6);
    if (unit < 392) {
      const int k = unit >> 3, dq = unit & 7;
      const ushort4 vv = vreg[u];
      vt[(4 * dq + 0) * 72 + k] = __builtin_bit_cast(__bf16, vv.x);
      vt[(4 * dq + 1) * 72 + k] = __builtin_bit_cast(__bf16, vv.y);
      vt[(4 * dq + 2) * 72 + k] = __builtin_bit_cast(__bf16, vv.z);
      vt[(4 * dq + 3) * 72 + k] = __builtin_bit_cast(__bf16, vv.w);
    }
  }

#pragma unroll
  for (int j = 0; j < 4; ++j) {
    float mx = -1e30f;
#pragma unroll
    for (int i = 0; i < 4; ++i)
#pragma unroll
      for (int r = 0; r < 4; ++r) mx = fmaxf(mx, acc[i][j][r]);
    mx = fmaxf(mx, __shfl_xor(mx, 16));
    mx = fmaxf(mx, __shfl_xor(mx, 32));
    float sum = 0.f;
#pragma unroll
    for (int i = 0; i < 4; ++i)
#pragma unroll
      for (int r = 0; r < 4; ++r) {
        const float e = __expf(acc[i][j][r] - mx);
        acc[i][j][r] = e;
        sum += e;
      }
    sum += __shfl_xor(sum, 16);
    sum += __shfl_xor(sum, 32);
    const float inv = 1.f / sum;
#pragma unroll
    for (int i = 0; i < 4; ++i) {
      ushort4 pk;
      pk.x = f2bfu(acc[i][j][0] * inv);
      pk.y = f2bfu(acc[i][j][1] * inv);
      pk.z = f2bfu(acc[i][j][2] * inv);
      pk.w = f2bfu(acc[i][j][3] * inv);
      *(ushort4*)&p_lds[(16 * j + lr) * 72 + 16 * i + 4 * g] = pk;
    }
  }

  f32x4 o[2][4] = {};
#pragma unroll
  for (int ks = 0; ks < 2; ++ks) {
    bf16x8 a2[2], b2[4];
#pragma unroll
    for (int i2 = 0; i2 < 2; ++i2)
      a2[i2] = *(const bf16x8*)&vt[(16 * i2 + lr) * 72 + 32 * ks + 8 * g];
#pragma unroll
    for (int j2 = 0; j2 < 4; ++j2)
      b2[j2] = *(const bf16x8*)&p_lds[(16 * j2 + lr) * 72 + 32 * ks + 8 * g];
#pragma unroll
    for (int i2 = 0; i2 < 2; ++i2)
#pragma unroll
      for (int j2 = 0; j2 < 4; ++j2)
        o[i2][j2] = __builtin_amdgcn_mfma_f32_16x16x32_bf16(a2[i2], b2[j2], o[i2][j2], 0, 0, 0);
  }

#pragma unroll
  for (int j2 = 0; j2 < 4; ++j2) {
    const int q = 16 * j2 + lr;
    if (q <= 48) {
#pragma unroll
      for (int i2 = 0; i2 < 2; ++i2) {
        ushort4 ok;
        ok.x = f2bfu(o[i2][j2][0]);
        ok.y = f2bfu(o[i2][j2][1]);
        ok.z = f2bfu(o[i2][j2][2]);
        ok.w = f2bfu(o[i2][j2][3]);
        *(ushort4*)&attnO[(rowbase + q) * DMODEL + h * 32 + 16 * i2 + 4 * g] = ok;
      }
    }
  }
}

extern "C" void kernel_launch(void* const* d_in, const int* in_sizes, int n_in,
                              void* d_out, int out_size, void* d_ws, size_t ws_size,
                              hipStream_t stream) {
  const float* x     = (const float*)d_in[0];
  const float* Wqkv  = (const float*)d_in[1];
  const float* bqkv  = (const float*)d_in[2];
  const float* Wproj = (const float*)d_in[3];
  const float* bproj = (const float*)d_in[4];
  float* out = (float*)d_out;

  char* ws = (char*)d_ws;
  __bf16* Xw     = (__bf16*)ws;  ws += (size_t)TOK * DMODEL * 2;   // 38.5 MB
  __bf16* qkvb   = (__bf16*)ws;  ws += (size_t)TOK * NQKV * 2;     // 115.6 MB
  __bf16* attnO  = (__bf16*)ws;  ws += (size_t)TOK * DMODEL * 2;   // 38.5 MB
  __bf16* attnP  = (__bf16*)ws;  ws += (size_t)TOK * DMODEL * 2;   // 38.5 MB
  __bf16* WqkvT  = (__bf16*)ws;  ws += (size_t)NQKV * DMODEL * 2;
  __bf16* WprojT = (__bf16*)ws;

  gather_x<<<dim3(8, 8, 16), 256, 0, stream>>>(x, Xw);
  conv_w<<<1728, 256, 0, stream>>>(Wqkv, Wproj, WqkvT, WprojT);
  gemm128<<<dim3(NQKV / 128, TOK / 128), 256, 0, stream>>>(Xw, WqkvT, bqkv, qkvb, NQKV);
  attn_mfma<<<dim3(NWIN, 12), 64, 0, stream>>>(qkvb, attnO);
  gemm128<<<dim3(DMODEL / 128, TOK / 128), 256, 0, stream>>>(attnO, WprojT, bproj, attnP, DMODEL);
  unscatter<<<dim3(8, 8, 16), 256, 0, stream>>>(attnP, out);
}

// Round 5
// 227.554 us; speedup vs baseline: 5.2300x; 1.0720x over previous
//
#include <hip/hip_runtime.h>

#define TOK     50176
#define NQKV    1152
#define DMODEL  384
#define HW      3136
#define NWIN    1024

typedef __bf16 bf16x8 __attribute__((ext_vector_type(8)));
typedef float  f32x4  __attribute__((ext_vector_type(4)));

__device__ __forceinline__ __bf16 f2bf(float f) {            // round-to-nearest-even
  unsigned u = __float_as_uint(f);
  u += 0x7fffu + ((u >> 16) & 1u);
  unsigned short s = (unsigned short)(u >> 16);
  return __builtin_bit_cast(__bf16, s);
}
__device__ __forceinline__ unsigned short f2bfu(float f) {
  return __builtin_bit_cast(unsigned short, f2bf(f));
}
__device__ __forceinline__ float bf2f(__bf16 b) {
  return __uint_as_float(((unsigned)__builtin_bit_cast(unsigned short, b)) << 16);
}
__device__ __forceinline__ void gload_lds16(const void* g, void* l) {
  __builtin_amdgcn_global_load_lds(
      (const __attribute__((address_space(1))) unsigned int*)g,
      (__attribute__((address_space(3))) unsigned int*)l, 16, 0, 0);
}

// ---------------------------------------------------------------------------
// Gather x (16,384,56,56) fp32 -> Xw (50176, 384) bf16 token-major.
// ---------------------------------------------------------------------------
__global__ __launch_bounds__(256) void gather_x(const float* __restrict__ x,
                                                __bf16* __restrict__ Xw) {
  __shared__ __bf16 lt[392 * 48];
  const int ct = blockIdx.x, hr = blockIdx.y, b = blockIdx.z;
  const int tid = threadIdx.x;
  const float* xb = x + ((size_t)(b * 384 + ct * 48)) * HW + hr * 7 * 56;

  for (int u = tid; u < 48 * 7 * 14; u += 256) {
    const int ch = u / 98, rem = u % 98;
    const int h7 = rem / 14, w4 = rem % 14;
    const float4 v = *(const float4*)&xb[(size_t)ch * HW + h7 * 56 + 4 * w4];
    const float vv[4] = {v.x, v.y, v.z, v.w};
#pragma unroll
    for (int e = 0; e < 4; ++e) {
      const int w = 4 * w4 + e;
      const int t = (w / 7) * 49 + h7 * 7 + (w % 7);
      lt[t * 48 + ch] = f2bf(vv[e]);
    }
  }
  __syncthreads();

  const size_t tokbase = (size_t)(b * 64 + hr * 8) * 49;
  for (int u = tid; u < 392 * 6; u += 256) {
    const int t = u / 6, c6 = u % 6;
    const bf16x8 vv = *(const bf16x8*)&lt[t * 48 + 8 * c6];
    *(bf16x8*)&Xw[(tokbase + t) * DMODEL + ct * 48 + 8 * c6] = vv;
  }
}

// ---------------------------------------------------------------------------
// Unscatter: attnP (50176,384) bf16 token-major -> out (16,384,56,56) fp32.
// ---------------------------------------------------------------------------
__global__ __launch_bounds__(256) void unscatter(const __bf16* __restrict__ P,
                                                 float* __restrict__ out) {
  __shared__ __bf16 lt[392 * 48];
  const int ct = blockIdx.x, hr = blockIdx.y, b = blockIdx.z;
  const int tid = threadIdx.x;
  const size_t tokbase = (size_t)(b * 64 + hr * 8) * 49;

  for (int u = tid; u < 392 * 6; u += 256) {
    const int t = u / 6, c6 = u % 6;
    *(bf16x8*)&lt[t * 48 + 8 * c6] =
        *(const bf16x8*)&P[(tokbase + t) * DMODEL + ct * 48 + 8 * c6];
  }
  __syncthreads();

  float* ob = out + ((size_t)(b * 384 + ct * 48)) * HW + hr * 7 * 56;
  for (int u = tid; u < 48 * 98; u += 256) {
    const int ch = u / 98, rem = u % 98;
    const int h7 = rem / 14, w4 = rem % 14;
    float4 o;
    float* oo = (float*)&o;
#pragma unroll
    for (int e = 0; e < 4; ++e) {
      const int w = 4 * w4 + e;
      const int t = (w / 7) * 49 + h7 * 7 + (w % 7);
      oo[e] = bf2f(lt[t * 48 + ch]);
    }
    *(float4*)&ob[(size_t)ch * HW + h7 * 56 + 4 * w4] = o;
  }
}

// Transpose+convert weights: WqkvT (1152,384) bf16, WprojT (384,384) bf16.
__global__ void conv_w(const float* __restrict__ Wqkv, const float* __restrict__ Wproj,
                       __bf16* __restrict__ WqkvT, __bf16* __restrict__ WprojT) {
  const int idx = blockIdx.x * 256 + threadIdx.x;
  if (idx < DMODEL * NQKV) {
    const int k = idx / NQKV, n = idx % NQKV;
    WqkvT[(size_t)n * DMODEL + k] = f2bf(Wqkv[idx]);
  }
  if (idx < DMODEL * DMODEL) {
    const int k = idx / DMODEL, n = idx % DMODEL;
    WprojT[(size_t)n * DMODEL + k] = f2bf(Wproj[idx]);
  }
}

// ---------------------------------------------------------------------------
// bf16 MFMA GEMM, 128x128 tile, BK=32, 256 threads, double-buffered LDS via
// global_load_lds. XCD-chunked work swizzle: each XCD owns a contiguous
// M-major chunk so the gridDim.x N-blocks sharing an A-panel hit the same
// XCD L2 (requires nwg % 8 == 0 -- true for 3528 and 1176).
// Transposed accumulator -> ushort4 packed bf16 stores + bias.
// ---------------------------------------------------------------------------
__global__ __launch_bounds__(256) void gemm128(const __bf16* __restrict__ A,
                                               const __bf16* __restrict__ BT,
                                               const float* __restrict__ bias,
                                               __bf16* __restrict__ Cout, int Ncols) {
  __shared__ __align__(16) __bf16 As[2][128 * 32];
  __shared__ __align__(16) __bf16 Bs[2][128 * 32];
  const int tid  = threadIdx.x;
  const int lane = tid & 63;
  const int wid  = tid >> 6;

  // XCD-chunked swizzle (bijective: nwg % 8 == 0)
  const int nwg  = gridDim.x * gridDim.y;
  const int orig = blockIdx.y * gridDim.x + blockIdx.x;
  const int cpx  = nwg >> 3;
  const int w    = (orig & 7) * cpx + (orig >> 3);
  const int bn   = (w % gridDim.x) << 7;
  const int bm   = (w / gridDim.x) << 7;

  const __bf16* a0 = A  + (size_t)(bm +      (tid >> 2)) * DMODEL + ((tid & 3) << 3);
  const __bf16* a1 = A  + (size_t)(bm + 64 + (tid >> 2)) * DMODEL + ((tid & 3) << 3);
  const __bf16* b0 = BT + (size_t)(bn +      (tid >> 2)) * DMODEL + ((tid & 3) << 3);
  const __bf16* b1 = BT + (size_t)(bn + 64 + (tid >> 2)) * DMODEL + ((tid & 3) << 3);

  const int wm = (wid >> 1) << 6;
  const int wn = (wid & 1) << 6;
  const int lrow = lane & 15;
  const int lk8  = (lane >> 4) << 3;

  f32x4 acc[4][4] = {};   // acc[j][i]: j = channel frag, i = token frag

  auto stage = [&](int buf, int kt) {
    const int koff = kt << 5;
    gload_lds16(a0 + koff, &As[buf][(wid << 9)]);
    gload_lds16(a1 + koff, &As[buf][2048 + (wid << 9)]);
    gload_lds16(b0 + koff, &Bs[buf][(wid << 9)]);
    gload_lds16(b1 + koff, &Bs[buf][2048 + (wid << 9)]);
  };

  stage(0, 0);
#pragma unroll 1
  for (int kt = 0; kt < 12; ++kt) {
    __syncthreads();
    if (kt + 1 < 12) stage((kt + 1) & 1, kt + 1);
    const __bf16* pA = &As[kt & 1][(wm + lrow) * 32 + lk8];
    const __bf16* pB = &Bs[kt & 1][(wn + lrow) * 32 + lk8];
    bf16x8 av[4], bv[4];
#pragma unroll
    for (int i = 0; i < 4; ++i) av[i] = *(const bf16x8*)(pA + i * 16 * 32);
#pragma unroll
    for (int j = 0; j < 4; ++j) bv[j] = *(const bf16x8*)(pB + j * 16 * 32);
#pragma unroll
    for (int i = 0; i < 4; ++i)
#pragma unroll
      for (int j = 0; j < 4; ++j)
        acc[j][i] = __builtin_amdgcn_mfma_f32_16x16x32_bf16(bv[j], av[i], acc[j][i], 0, 0, 0);
  }

  const int lr = lane & 15, g = lane >> 4;
  const int tok0 = bm + wm + lr;
  const int ch0  = bn + wn + (g << 2);

#pragma unroll
  for (int j = 0; j < 4; ++j) {
    const int ch = ch0 + 16 * j;
    const float4 b4 = *(const float4*)&bias[ch];
#pragma unroll
    for (int i = 0; i < 4; ++i) {
      const int token = tok0 + 16 * i;
      ushort4 pk;
      pk.x = f2bfu(acc[j][i][0] + b4.x);
      pk.y = f2bfu(acc[j][i][1] + b4.y);
      pk.z = f2bfu(acc[j][i][2] + b4.z);
      pk.w = f2bfu(acc[j][i][3] + b4.w);
      *(ushort4*)&Cout[(size_t)token * Ncols + ch] = pk;
    }
  }
}

// ---------------------------------------------------------------------------
// MFMA attention: one wave per (window, head). Pad 49 -> 64. (unchanged)
// ---------------------------------------------------------------------------
__global__ __launch_bounds__(64) void attn_mfma(const __bf16* __restrict__ qkv,
                                                __bf16* __restrict__ attnO) {
  __shared__ __align__(16) __bf16 lds[96 * 72];
  __bf16* p_lds = lds;
  __bf16* vt    = lds + 64 * 72;

  const int lane = threadIdx.x;
  const int win  = blockIdx.x;
  const int h    = blockIdx.y;
  const int lr = lane & 15, g = lane >> 4;
  const size_t rowbase = (size_t)win * 49;

  int rr[4];
#pragma unroll
  for (int f = 0; f < 4; ++f) rr[f] = (16 * f + lr > 48) ? 48 : (16 * f + lr);

  const int co = h * 32 + 8 * g;

  bf16x8 av[4], bv[4];
#pragma unroll
  for (int f = 0; f < 4; ++f) {
    const __bf16* rp = qkv + (rowbase + rr[f]) * NQKV + co;
    av[f] = *(const bf16x8*)(rp + 384);
    bv[f] = *(const bf16x8*)(rp);
  }

  ushort4 vreg[7];
#pragma unroll
  for (int u = 0; u < 7; ++u) {
    const int unit = lane + (u << 6);
    if (unit < 392) {
      const int k = unit >> 3, dq = unit & 7;
      vreg[u] = *(const ushort4*)(qkv + (rowbase + k) * NQKV + 768 + h * 32 + 4 * dq);
    }
  }

  f32x4 acc[4][4] = {};
#pragma unroll
  for (int i = 0; i < 4; ++i)
#pragma unroll
    for (int j = 0; j < 4; ++j)
      acc[i][j] = __builtin_amdgcn_mfma_f32_16x16x32_bf16(av[i], bv[j], acc[i][j], 0, 0, 0);

  const float scale = 0.17677669529663687f;
#pragma unroll
  for (int i = 0; i < 4; ++i)
#pragma unroll
    for (int j = 0; j < 4; ++j)
#pragma unroll
      for (int r = 0; r < 4; ++r) {
        float v = acc[i][j][r] * scale;
        if (i == 3 && (4 * g + r) != 0) v = -1e30f;
        acc[i][j][r] = v;
      }

#pragma unroll
  for (int u = 0; u < 7; ++u) {
    const int unit = lane + (u << 6);
    if (unit < 392) {
      const int k = unit >> 3, dq = unit & 7;
      const ushort4 vv = vreg[u];
      vt[(4 * dq + 0) * 72 + k] = __builtin_bit_cast(__bf16, vv.x);
      vt[(4 * dq + 1) * 72 + k] = __builtin_bit_cast(__bf16, vv.y);
      vt[(4 * dq + 2) * 72 + k] = __builtin_bit_cast(__bf16, vv.z);
      vt[(4 * dq + 3) * 72 + k] = __builtin_bit_cast(__bf16, vv.w);
    }
  }

#pragma unroll
  for (int j = 0; j < 4; ++j) {
    float mx = -1e30f;
#pragma unroll
    for (int i = 0; i < 4; ++i)
#pragma unroll
      for (int r = 0; r < 4; ++r) mx = fmaxf(mx, acc[i][j][r]);
    mx = fmaxf(mx, __shfl_xor(mx, 16));
    mx = fmaxf(mx, __shfl_xor(mx, 32));
    float sum = 0.f;
#pragma unroll
    for (int i = 0; i < 4; ++i)
#pragma unroll
      for (int r = 0; r < 4; ++r) {
        const float e = __expf(acc[i][j][r] - mx);
        acc[i][j][r] = e;
        sum += e;
      }
    sum += __shfl_xor(sum, 16);
    sum += __shfl_xor(sum, 32);
    const float inv = 1.f / sum;
#pragma unroll
    for (int i = 0; i < 4; ++i) {
      ushort4 pk;
      pk.x = f2bfu(acc[i][j][0] * inv);
      pk.y = f2bfu(acc[i][j][1] * inv);
      pk.z = f2bfu(acc[i][j][2] * inv);
      pk.w = f2bfu(acc[i][j][3] * inv);
      *(ushort4*)&p_lds[(16 * j + lr) * 72 + 16 * i + 4 * g] = pk;
    }
  }

  f32x4 o[2][4] = {};
#pragma unroll
  for (int ks = 0; ks < 2; ++ks) {
    bf16x8 a2[2], b2[4];
#pragma unroll
    for (int i2 = 0; i2 < 2; ++i2)
      a2[i2] = *(const bf16x8*)&vt[(16 * i2 + lr) * 72 + 32 * ks + 8 * g];
#pragma unroll
    for (int j2 = 0; j2 < 4; ++j2)
      b2[j2] = *(const bf16x8*)&p_lds[(16 * j2 + lr) * 72 + 32 * ks + 8 * g];
#pragma unroll
    for (int i2 = 0; i2 < 2; ++i2)
#pragma unroll
      for (int j2 = 0; j2 < 4; ++j2)
        o[i2][j2] = __builtin_amdgcn_mfma_f32_16x16x32_bf16(a2[i2], b2[j2], o[i2][j2], 0, 0, 0);
  }

#pragma unroll
  for (int j2 = 0; j2 < 4; ++j2) {
    const int q = 16 * j2 + lr;
    if (q <= 48) {
#pragma unroll
      for (int i2 = 0; i2 < 2; ++i2) {
        ushort4 ok;
        ok.x = f2bfu(o[i2][j2][0]);
        ok.y = f2bfu(o[i2][j2][1]);
        ok.z = f2bfu(o[i2][j2][2]);
        ok.w = f2bfu(o[i2][j2][3]);
        *(ushort4*)&attnO[(rowbase + q) * DMODEL + h * 32 + 16 * i2 + 4 * g] = ok;
      }
    }
  }
}

extern "C" void kernel_launch(void* const* d_in, const int* in_sizes, int n_in,
                              void* d_out, int out_size, void* d_ws, size_t ws_size,
                              hipStream_t stream) {
  const float* x     = (const float*)d_in[0];
  const float* Wqkv  = (const float*)d_in[1];
  const float* bqkv  = (const float*)d_in[2];
  const float* Wproj = (const float*)d_in[3];
  const float* bproj = (const float*)d_in[4];
  float* out = (float*)d_out;

  char* ws = (char*)d_ws;
  __bf16* Xw     = (__bf16*)ws;  ws += (size_t)TOK * DMODEL * 2;   // 38.5 MB
  __bf16* qkvb   = (__bf16*)ws;  ws += (size_t)TOK * NQKV * 2;     // 115.6 MB
  __bf16* attnO  = (__bf16*)ws;  ws += (size_t)TOK * DMODEL * 2;   // 38.5 MB
  __bf16* attnP  = (__bf16*)ws;  ws += (size_t)TOK * DMODEL * 2;   // 38.5 MB
  __bf16* WqkvT  = (__bf16*)ws;  ws += (size_t)NQKV * DMODEL * 2;
  __bf16* WprojT = (__bf16*)ws;

  gather_x<<<dim3(8, 8, 16), 256, 0, stream>>>(x, Xw);
  conv_w<<<1728, 256, 0, stream>>>(Wqkv, Wproj, WqkvT, WprojT);
  gemm128<<<dim3(NQKV / 128, TOK / 128), 256, 0, stream>>>(Xw, WqkvT, bqkv, qkvb, NQKV);
  attn_mfma<<<dim3(NWIN, 12), 64, 0, stream>>>(qkvb, attnO);
  gemm128<<<dim3(DMODEL / 128, TOK / 128), 256, 0, stream>>>(attnO, WprojT, bproj, attnP, DMODEL);
  unscatter<<<dim3(8, 8, 16), 256, 0, stream>>>(attnP, out);
}

// Round 6
// 226.908 us; speedup vs baseline: 5.2449x; 1.0028x over previous
//
#include <hip/hip_runtime.h>

#define TOK     50176
#define NQKV    1152
#define DMODEL  384
#define HW      3136
#define NWIN    1024

typedef __bf16 bf16x8 __attribute__((ext_vector_type(8)));
typedef float  f32x4  __attribute__((ext_vector_type(4)));

__device__ __forceinline__ __bf16 f2bf(float f) {            // round-to-nearest-even
  unsigned u = __float_as_uint(f);
  u += 0x7fffu + ((u >> 16) & 1u);
  unsigned short s = (unsigned short)(u >> 16);
  return __builtin_bit_cast(__bf16, s);
}
__device__ __forceinline__ unsigned short f2bfu(float f) {
  return __builtin_bit_cast(unsigned short, f2bf(f));
}
__device__ __forceinline__ float bf2f(__bf16 b) {
  return __uint_as_float(((unsigned)__builtin_bit_cast(unsigned short, b)) << 16);
}
__device__ __forceinline__ void gload_lds16(const void* g, void* l) {
  __builtin_amdgcn_global_load_lds(
      (const __attribute__((address_space(1))) unsigned int*)g,
      (__attribute__((address_space(3))) unsigned int*)l, 16, 0, 0);
}

// ---------------------------------------------------------------------------
// Gather x (16,384,56,56) fp32 -> Xw (50176, 384) bf16 token-major.
// ---------------------------------------------------------------------------
__global__ __launch_bounds__(256) void gather_x(const float* __restrict__ x,
                                                __bf16* __restrict__ Xw) {
  __shared__ __bf16 lt[392 * 48];
  const int ct = blockIdx.x, hr = blockIdx.y, b = blockIdx.z;
  const int tid = threadIdx.x;
  const float* xb = x + ((size_t)(b * 384 + ct * 48)) * HW + hr * 7 * 56;

  for (int u = tid; u < 48 * 7 * 14; u += 256) {
    const int ch = u / 98, rem = u % 98;
    const int h7 = rem / 14, w4 = rem % 14;
    const float4 v = *(const float4*)&xb[(size_t)ch * HW + h7 * 56 + 4 * w4];
    const float vv[4] = {v.x, v.y, v.z, v.w};
#pragma unroll
    for (int e = 0; e < 4; ++e) {
      const int w = 4 * w4 + e;
      const int t = (w / 7) * 49 + h7 * 7 + (w % 7);
      lt[t * 48 + ch] = f2bf(vv[e]);
    }
  }
  __syncthreads();

  const size_t tokbase = (size_t)(b * 64 + hr * 8) * 49;
  for (int u = tid; u < 392 * 6; u += 256) {
    const int t = u / 6, c6 = u % 6;
    const bf16x8 vv = *(const bf16x8*)&lt[t * 48 + 8 * c6];
    *(bf16x8*)&Xw[(tokbase + t) * DMODEL + ct * 48 + 8 * c6] = vv;
  }
}

// ---------------------------------------------------------------------------
// Unscatter: attnP (50176,384) bf16 token-major -> out (16,384,56,56) fp32.
// ---------------------------------------------------------------------------
__global__ __launch_bounds__(256) void unscatter(const __bf16* __restrict__ P,
                                                 float* __restrict__ out) {
  __shared__ __bf16 lt[392 * 48];
  const int ct = blockIdx.x, hr = blockIdx.y, b = blockIdx.z;
  const int tid = threadIdx.x;
  const size_t tokbase = (size_t)(b * 64 + hr * 8) * 49;

  for (int u = tid; u < 392 * 6; u += 256) {
    const int t = u / 6, c6 = u % 6;
    *(bf16x8*)&lt[t * 48 + 8 * c6] =
        *(const bf16x8*)&P[(tokbase + t) * DMODEL + ct * 48 + 8 * c6];
  }
  __syncthreads();

  float* ob = out + ((size_t)(b * 384 + ct * 48)) * HW + hr * 7 * 56;
  for (int u = tid; u < 48 * 98; u += 256) {
    const int ch = u / 98, rem = u % 98;
    const int h7 = rem / 14, w4 = rem % 14;
    float4 o;
    float* oo = (float*)&o;
#pragma unroll
    for (int e = 0; e < 4; ++e) {
      const int w = 4 * w4 + e;
      const int t = (w / 7) * 49 + h7 * 7 + (w % 7);
      oo[e] = bf2f(lt[t * 48 + ch]);
    }
    *(float4*)&ob[(size_t)ch * HW + h7 * 56 + 4 * w4] = o;
  }
}

// Transpose+convert weights: WqkvT (1152,384) bf16, WprojT (384,384) bf16.
__global__ void conv_w(const float* __restrict__ Wqkv, const float* __restrict__ Wproj,
                       __bf16* __restrict__ WqkvT, __bf16* __restrict__ WprojT) {
  const int idx = blockIdx.x * 256 + threadIdx.x;
  if (idx < DMODEL * NQKV) {
    const int k = idx / NQKV, n = idx % NQKV;
    WqkvT[(size_t)n * DMODEL + k] = f2bf(Wqkv[idx]);
  }
  if (idx < DMODEL * DMODEL) {
    const int k = idx / DMODEL, n = idx % DMODEL;
    WprojT[(size_t)n * DMODEL + k] = f2bf(Wproj[idx]);
  }
}

// ---------------------------------------------------------------------------
// bf16 MFMA GEMM, 256x128 tile, BK=32, 512 threads (8 waves: 4M x 2N, each
// wave 64x64), double-buffered LDS via global_load_lds. Same 2-phase sync
// structure as before (proven); bigger tile amortizes prologue/epilogue and
// doubles MFMA per staged byte. Bijective XCD-chunk swizzle (nwg%8 != 0).
// Transposed accumulator -> ushort4 packed bf16 stores + bias.
// ---------------------------------------------------------------------------
__global__ __launch_bounds__(512) void gemm256(const __bf16* __restrict__ A,
                                               const __bf16* __restrict__ BT,
                                               const float* __restrict__ bias,
                                               __bf16* __restrict__ Cout, int Ncols) {
  __shared__ __align__(16) __bf16 As[2][256 * 32];
  __shared__ __align__(16) __bf16 Bs[2][128 * 32];
  const int tid  = threadIdx.x;
  const int lane = tid & 63;
  const int wid  = tid >> 6;

  // bijective XCD-chunked swizzle (m204 variant; works for any nwg)
  const int nwg  = gridDim.x * gridDim.y;
  const int orig = blockIdx.y * gridDim.x + blockIdx.x;
  const int q    = nwg >> 3, r = nwg & 7;
  const int xcd  = orig & 7, pos = orig >> 3;
  const int start = (xcd < r) ? xcd * (q + 1) : r * (q + 1) + (xcd - r) * q;
  const int w    = start + pos;
  const int bn   = (w % gridDim.x) << 7;   // N tile: 128
  const int bm   = (w / gridDim.x) << 8;   // M tile: 256

  // staging sources: 512 threads cover 128 rows x 32 cols per instruction
  const __bf16* a0 = A  + (size_t)(bm +       (tid >> 2)) * DMODEL + ((tid & 3) << 3);
  const __bf16* a1 = A  + (size_t)(bm + 128 + (tid >> 2)) * DMODEL + ((tid & 3) << 3);
  const __bf16* b0 = BT + (size_t)(bn +       (tid >> 2)) * DMODEL + ((tid & 3) << 3);

  const int wm = (wid >> 1) << 6;   // 0,64,128,192
  const int wn = (wid & 1) << 6;    // 0,64
  const int lrow = lane & 15;
  const int lk8  = (lane >> 4) << 3;

  f32x4 acc[4][4] = {};   // acc[j][i]: j = channel frag, i = token frag

  auto stage = [&](int buf, int kt) {
    const int koff = kt << 5;
    gload_lds16(a0 + koff, &As[buf][(wid << 9)]);
    gload_lds16(a1 + koff, &As[buf][4096 + (wid << 9)]);
    gload_lds16(b0 + koff, &Bs[buf][(wid << 9)]);
  };

  stage(0, 0);
#pragma unroll 1
  for (int kt = 0; kt < 12; ++kt) {
    __syncthreads();
    if (kt + 1 < 12) stage((kt + 1) & 1, kt + 1);
    const __bf16* pA = &As[kt & 1][(wm + lrow) * 32 + lk8];
    const __bf16* pB = &Bs[kt & 1][(wn + lrow) * 32 + lk8];
    bf16x8 av[4], bv[4];
#pragma unroll
    for (int i = 0; i < 4; ++i) av[i] = *(const bf16x8*)(pA + i * 16 * 32);
#pragma unroll
    for (int j = 0; j < 4; ++j) bv[j] = *(const bf16x8*)(pB + j * 16 * 32);
#pragma unroll
    for (int i = 0; i < 4; ++i)
#pragma unroll
      for (int j = 0; j < 4; ++j)
        acc[j][i] = __builtin_amdgcn_mfma_f32_16x16x32_bf16(bv[j], av[i], acc[j][i], 0, 0, 0);
  }

  const int lr = lane & 15, g = lane >> 4;
  const int tok0 = bm + wm + lr;
  const int ch0  = bn + wn + (g << 2);

#pragma unroll
  for (int j = 0; j < 4; ++j) {
    const int ch = ch0 + 16 * j;
    const float4 b4 = *(const float4*)&bias[ch];
#pragma unroll
    for (int i = 0; i < 4; ++i) {
      const int token = tok0 + 16 * i;
      ushort4 pk;
      pk.x = f2bfu(acc[j][i][0] + b4.x);
      pk.y = f2bfu(acc[j][i][1] + b4.y);
      pk.z = f2bfu(acc[j][i][2] + b4.z);
      pk.w = f2bfu(acc[j][i][3] + b4.w);
      *(ushort4*)&Cout[(size_t)token * Ncols + ch] = pk;
    }
  }
}

// ---------------------------------------------------------------------------
// MFMA attention: one wave per (window, head). Pad 49 -> 64. (unchanged)
// ---------------------------------------------------------------------------
__global__ __launch_bounds__(64) void attn_mfma(const __bf16* __restrict__ qkv,
                                                __bf16* __restrict__ attnO) {
  __shared__ __align__(16) __bf16 lds[96 * 72];
  __bf16* p_lds = lds;
  __bf16* vt    = lds + 64 * 72;

  const int lane = threadIdx.x;
  const int win  = blockIdx.x;
  const int h    = blockIdx.y;
  const int lr = lane & 15, g = lane >> 4;
  const size_t rowbase = (size_t)win * 49;

  int rr[4];
#pragma unroll
  for (int f = 0; f < 4; ++f) rr[f] = (16 * f + lr > 48) ? 48 : (16 * f + lr);

  const int co = h * 32 + 8 * g;

  bf16x8 av[4], bv[4];
#pragma unroll
  for (int f = 0; f < 4; ++f) {
    const __bf16* rp = qkv + (rowbase + rr[f]) * NQKV + co;
    av[f] = *(const bf16x8*)(rp + 384);
    bv[f] = *(const bf16x8*)(rp);
  }

  ushort4 vreg[7];
#pragma unroll
  for (int u = 0; u < 7; ++u) {
    const int unit = lane + (u << 6);
    if (unit < 392) {
      const int k = unit >> 3, dq = unit & 7;
      vreg[u] = *(const ushort4*)(qkv + (rowbase + k) * NQKV + 768 + h * 32 + 4 * dq);
    }
  }

  f32x4 acc[4][4] = {};
#pragma unroll
  for (int i = 0; i < 4; ++i)
#pragma unroll
    for (int j = 0; j < 4; ++j)
      acc[i][j] = __builtin_amdgcn_mfma_f32_16x16x32_bf16(av[i], bv[j], acc[i][j], 0, 0, 0);

  const float scale = 0.17677669529663687f;
#pragma unroll
  for (int i = 0; i < 4; ++i)
#pragma unroll
    for (int j = 0; j < 4; ++j)
#pragma unroll
      for (int r = 0; r < 4; ++r) {
        float v = acc[i][j][r] * scale;
        if (i == 3 && (4 * g + r) != 0) v = -1e30f;
        acc[i][j][r] = v;
      }

#pragma unroll
  for (int u = 0; u < 7; ++u) {
    const int unit = lane + (u << 6);
    if (unit < 392) {
      const int k = unit >> 3, dq = unit & 7;
      const ushort4 vv = vreg[u];
      vt[(4 * dq + 0) * 72 + k] = __builtin_bit_cast(__bf16, vv.x);
      vt[(4 * dq + 1) * 72 + k] = __builtin_bit_cast(__bf16, vv.y);
      vt[(4 * dq + 2) * 72 + k] = __builtin_bit_cast(__bf16, vv.z);
      vt[(4 * dq + 3) * 72 + k] = __builtin_bit_cast(__bf16, vv.w);
    }
  }

#pragma unroll
  for (int j = 0; j < 4; ++j) {
    float mx = -1e30f;
#pragma unroll
    for (int i = 0; i < 4; ++i)
#pragma unroll
      for (int r = 0; r < 4; ++r) mx = fmaxf(mx, acc[i][j][r]);
    mx = fmaxf(mx, __shfl_xor(mx, 16));
    mx = fmaxf(mx, __shfl_xor(mx, 32));
    float sum = 0.f;
#pragma unroll
    for (int i = 0; i < 4; ++i)
#pragma unroll
      for (int r = 0; r < 4; ++r) {
        const float e = __expf(acc[i][j][r] - mx);
        acc[i][j][r] = e;
        sum += e;
      }
    sum += __shfl_xor(sum, 16);
    sum += __shfl_xor(sum, 32);
    const float inv = 1.f / sum;
#pragma unroll
    for (int i = 0; i < 4; ++i) {
      ushort4 pk;
      pk.x = f2bfu(acc[i][j][0] * inv);
      pk.y = f2bfu(acc[i][j][1] * inv);
      pk.z = f2bfu(acc[i][j][2] * inv);
      pk.w = f2bfu(acc[i][j][3] * inv);
      *(ushort4*)&p_lds[(16 * j + lr) * 72 + 16 * i + 4 * g] = pk;
    }
  }

  f32x4 o[2][4] = {};
#pragma unroll
  for (int ks = 0; ks < 2; ++ks) {
    bf16x8 a2[2], b2[4];
#pragma unroll
    for (int i2 = 0; i2 < 2; ++i2)
      a2[i2] = *(const bf16x8*)&vt[(16 * i2 + lr) * 72 + 32 * ks + 8 * g];
#pragma unroll
    for (int j2 = 0; j2 < 4; ++j2)
      b2[j2] = *(const bf16x8*)&p_lds[(16 * j2 + lr) * 72 + 32 * ks + 8 * g];
#pragma unroll
    for (int i2 = 0; i2 < 2; ++i2)
#pragma unroll
      for (int j2 = 0; j2 < 4; ++j2)
        o[i2][j2] = __builtin_amdgcn_mfma_f32_16x16x32_bf16(a2[i2], b2[j2], o[i2][j2], 0, 0, 0);
  }

#pragma unroll
  for (int j2 = 0; j2 < 4; ++j2) {
    const int q = 16 * j2 + lr;
    if (q <= 48) {
#pragma unroll
      for (int i2 = 0; i2 < 2; ++i2) {
        ushort4 ok;
        ok.x = f2bfu(o[i2][j2][0]);
        ok.y = f2bfu(o[i2][j2][1]);
        ok.z = f2bfu(o[i2][j2][2]);
        ok.w = f2bfu(o[i2][j2][3]);
        *(ushort4*)&attnO[(rowbase + q) * DMODEL + h * 32 + 16 * i2 + 4 * g] = ok;
      }
    }
  }
}

extern "C" void kernel_launch(void* const* d_in, const int* in_sizes, int n_in,
                              void* d_out, int out_size, void* d_ws, size_t ws_size,
                              hipStream_t stream) {
  const float* x     = (const float*)d_in[0];
  const float* Wqkv  = (const float*)d_in[1];
  const float* bqkv  = (const float*)d_in[2];
  const float* Wproj = (const float*)d_in[3];
  const float* bproj = (const float*)d_in[4];
  float* out = (float*)d_out;

  char* ws = (char*)d_ws;
  __bf16* Xw     = (__bf16*)ws;  ws += (size_t)TOK * DMODEL * 2;   // 38.5 MB
  __bf16* qkvb   = (__bf16*)ws;  ws += (size_t)TOK * NQKV * 2;     // 115.6 MB
  __bf16* attnO  = (__bf16*)ws;  ws += (size_t)TOK * DMODEL * 2;   // 38.5 MB
  __bf16* attnP  = (__bf16*)ws;  ws += (size_t)TOK * DMODEL * 2;   // 38.5 MB
  __bf16* WqkvT  = (__bf16*)ws;  ws += (size_t)NQKV * DMODEL * 2;
  __bf16* WprojT = (__bf16*)ws;

  gather_x<<<dim3(8, 8, 16), 256, 0, stream>>>(x, Xw);
  conv_w<<<1728, 256, 0, stream>>>(Wqkv, Wproj, WqkvT, WprojT);
  gemm256<<<dim3(NQKV / 128, TOK / 256), 512, 0, stream>>>(Xw, WqkvT, bqkv, qkvb, NQKV);
  attn_mfma<<<dim3(NWIN, 12), 64, 0, stream>>>(qkvb, attnO);
  gemm256<<<dim3(DMODEL / 128, TOK / 256), 512, 0, stream>>>(attnO, WprojT, bproj, attnP, DMODEL);
  unscatter<<<dim3(8, 8, 16), 256, 0, stream>>>(attnP, out);
}